// Round 6
// baseline (580.656 us; speedup 1.0000x reference)
//
#include <hip/hip_runtime.h>
#include <hip/hip_bf16.h>
#include <stdint.h>

// DecoderBlock: x + attn(LN1(x)) -> x2; x2 + FFN(LN2(x2))
// B=4, T=2048, HIDDEN=1024, HEADS=16, HEAD=64, DFF=4096
// Round 6: (1) GEMMs unified on per-wave 128x64 geometry (MFMA-bound, not
// LDS-bound), ring-3 counted-vmcnt pipeline; 8-wave 256x256 blocks for
// QKV/FF1, 4-wave 256x128 blocks for Wo/FF2 (N=1024 -> full 256-block grids).
// (2) Attention: paired q-tiles (k, 15-k) -> uniform 36 tiles/block, grid 8x64.

#define HID 1024
#define NH 16
#define HD 64
#define DFF 4096
#define BATCH 4
#define SEQ 2048
#define NTOK (BATCH*SEQ)   // 8192

typedef unsigned short u16;
typedef unsigned int u32;
typedef __attribute__((ext_vector_type(4))) float f32x4;
typedef __attribute__((ext_vector_type(16))) float f32x16;
typedef __attribute__((ext_vector_type(8))) __bf16 bf16x8;

__device__ __forceinline__ u16 f2bf(float f) {
    unsigned int u = __float_as_uint(f);
    u = (u + 0x7fffu + ((u >> 16) & 1u)) >> 16;   // RNE
    return (u16)u;
}

__device__ __forceinline__ u32 cvtpk(float lo, float hi) {
    u32 d;
    asm("v_cvt_pk_bf16_f32 %0, %1, %2" : "=v"(d) : "v"(lo), "v"(hi));
    return d;
}

__device__ __forceinline__ void plswap(u32& a, u32& b) {
    asm volatile("v_permlane32_swap_b32 %0, %1" : "+v"(a), "+v"(b));
}

__device__ __forceinline__ void gload_lds16(const void* g, void* lds) {
    __builtin_amdgcn_global_load_lds(
        (const __attribute__((address_space(1))) unsigned int*)(uintptr_t)g,
        (__attribute__((address_space(3))) unsigned int*)(uintptr_t)lds, 16, 0, 0);
}

template <int N>
__device__ __forceinline__ void waitvm() {
    if constexpr (N == 6)      asm volatile("s_waitcnt vmcnt(6)" ::: "memory");
    else if constexpr (N == 4) asm volatile("s_waitcnt vmcnt(4)" ::: "memory");
    else                       asm volatile("s_waitcnt vmcnt(0)" ::: "memory");
}

__device__ __forceinline__ void pipe_barrier() {
    __builtin_amdgcn_sched_barrier(0);
    __builtin_amdgcn_s_barrier();
    __builtin_amdgcn_sched_barrier(0);
}

// ---------------- LayerNorm: f32 in -> bf16 out ----------------
__global__ __launch_bounds__(256) void ln_kernel(const float* __restrict__ x,
                                                 const float* __restrict__ g,
                                                 const float* __restrict__ be,
                                                 u16* __restrict__ out) {
    __shared__ float red[10];
    const int row = blockIdx.x, tid = threadIdx.x;
    const float4 v = ((const float4*)(x + (size_t)row * HID))[tid];
    float s  = v.x + v.y + v.z + v.w;
    float s2 = v.x*v.x + v.y*v.y + v.z*v.z + v.w*v.w;
    for (int off = 32; off > 0; off >>= 1) {
        s  += __shfl_down(s, off, 64);
        s2 += __shfl_down(s2, off, 64);
    }
    if ((tid & 63) == 0) { red[tid >> 6] = s; red[4 + (tid >> 6)] = s2; }
    __syncthreads();
    if (tid == 0) {
        red[8] = red[0] + red[1] + red[2] + red[3];
        red[9] = red[4] + red[5] + red[6] + red[7];
    }
    __syncthreads();
    const float mu  = red[8] * (1.f / HID);
    const float var = red[9] * (1.f / HID) - mu * mu;
    const float rstd = rsqrtf(var + 1e-5f);
    const float4 g4 = ((const float4*)g)[tid];
    const float4 b4 = ((const float4*)be)[tid];
    ushort4 o;
    o.x = f2bf((v.x - mu) * rstd * g4.x + b4.x);
    o.y = f2bf((v.y - mu) * rstd * g4.y + b4.y);
    o.z = f2bf((v.z - mu) * rstd * g4.z + b4.z);
    o.w = f2bf((v.w - mu) * rstd * g4.w + b4.w);
    ((ushort4*)(out + (size_t)row * HID))[tid] = o;
}

// ---------------- weight transpose+cast: out[c][r] = (bf16)in[r][c], batched ----------------
__global__ __launch_bounds__(256) void transpose_w(const float* __restrict__ in,
                                                   u16* __restrict__ out, int R, int C) {
    __shared__ float t[32][33];
    const int r0 = blockIdx.x * 32, c0 = blockIdx.y * 32;
    const float* inb = in + (size_t)blockIdx.z * R * C;
    u16* outb = out + (size_t)blockIdx.z * R * C;
    const int tid = threadIdx.x;
    const int tr = tid >> 3, tc = (tid & 7) * 4;
    const float4 v = *(const float4*)&inb[(size_t)(r0 + tr) * C + c0 + tc];
    t[tr][tc] = v.x; t[tr][tc + 1] = v.y; t[tr][tc + 2] = v.z; t[tr][tc + 3] = v.w;
    __syncthreads();
    ushort4 o;
    o.x = f2bf(t[tc + 0][tr]);
    o.y = f2bf(t[tc + 1][tr]);
    o.z = f2bf(t[tc + 2][tr]);
    o.w = f2bf(t[tc + 3][tr]);
    *(ushort4*)&outb[(size_t)(c0 + tr) * R + r0 + tc] = o;
}

// ---------------- V transpose (bf16): [bh][T][64] -> [bh][64][T] ----------------
__global__ __launch_bounds__(256) void transpose_v(const u16* __restrict__ in,
                                                   u16* __restrict__ out) {
    __shared__ u16 t[64][65];
    const int s0 = blockIdx.x * 64;
    const size_t bh = blockIdx.y;
    const u16* inb = in + bh * SEQ * HD;
    u16* outb = out + bh * HD * SEQ;
    const int tid = threadIdx.x;
    const int r = tid >> 2, c = (tid & 3) * 16;
    bf16x8 a = *(const bf16x8*)&inb[(size_t)(s0 + r) * HD + c];
    bf16x8 b = *(const bf16x8*)&inb[(size_t)(s0 + r) * HD + c + 8];
    #pragma unroll
    for (int i = 0; i < 8; i++) {
        t[r][c + i]     = ((const u16*)&a)[i];
        t[r][c + 8 + i] = ((const u16*)&b)[i];
    }
    __syncthreads();
    u16 o0[8], o1[8];
    #pragma unroll
    for (int i = 0; i < 8; i++) { o0[i] = t[c + i][r]; o1[i] = t[c + 8 + i][r]; }
    *(bf16x8*)&outb[(size_t)r * SEQ + s0 + c]     = *(const bf16x8*)o0;
    *(bf16x8*)&outb[(size_t)r * SEQ + s0 + c + 8] = *(const bf16x8*)o1;
}

// ---------------- unified pipelined GEMM, per-wave 128x64 ----------------
// C[M][N] = A[M][K](bf16,rm) * B^T[N][K](bf16,rm). BM=256; WAVES=8 -> BN=256
// (2M x 4N waves), WAVES=4 -> BN=128 (2M x 2N). Per-wave output 128x64
// (acc[8][4]) = 43.7 FLOP per LDS-read-byte -> MFMA-bound.
// K in 32-wide steps, ring of 3 LDS slices: iter h computes slot h%3, stages
// h+2 into slot (h+2)%3 (read-retired in iter h-1), vmcnt(LPS) retires h+1's
// own loads, s_barrier globalizes (T3+T4; never drains in steady state).
// LDS slice: 128B line L = rows (L, L+LINES) paired in 64B halves, XOR-swizzled
// ((row&7)<<4); staged via pre-swizzled global source (rule 21).
// MODE 0: QKV scatter (which=c>>10, Q*0.125)  MODE 1: f32 resid+bias  MODE 2: ReLU bf16
template <int WAVES, int MODE>
__global__ __launch_bounds__(WAVES * 64, 2) void gemm6(const u16* __restrict__ A,
                                                       const u16* __restrict__ B,
                                                       float* __restrict__ outf,
                                                       u16* __restrict__ outh,
                                                       const float* __restrict__ bias,
                                                       const float* __restrict__ resid,
                                                       int K, int N) {
    constexpr int THREADS = WAVES * 64;
    constexpr int WN  = WAVES / 2;            // N-waves
    constexpr int BN  = WN * 64;
    constexpr int ASL = 16384;                // 256 rows x 32K x 2B
    constexpr int BSL = BN * 64;              // BN rows x 32K x 2B
    constexpr int ARD = ASL / (THREADS * 16); // staging rounds
    constexpr int BRD = BSL / (THREADS * 16);
    constexpr int LPS = ARD + BRD;            // own loads per stage
    constexpr int LB  = BSL >> 7;             // B lines per slice
    __shared__ char lds[3 * (ASL + BSL)];
    char* const ldsB = lds + 3 * ASL;

    const int tid = threadIdx.x;
    const int w = tid >> 6, l = tid & 63;
    const int l15 = l & 15, lg = l >> 4;
    const int wr = w / WN, wc = w % WN;

    // XCD-contiguous block swizzle (all grids are multiples of 8)
    const int nwg = gridDim.x;
    const int wg = (blockIdx.x & 7) * (nwg >> 3) + (blockIdx.x >> 3);
    const int m0 = (wg & 31) * 256;           // M = 8192 always
    const int n0 = (wg >> 5) * BN;
    const size_t Kb = (size_t)K * 2;
    const int H = K >> 5;

    // staging source precompute: invert swizzled LDS layout at linear pos p
    int gar[ARD], gac[ARD], gbr[BRD], gbc[BRD];
    #pragma unroll
    for (int rd = 0; rd < ARD; ++rd) {
        const int p = rd * (THREADS * 16) + tid * 16;
        const int line = p >> 7, s16 = (p >> 4) & 7;
        const int u = (s16 * 16) ^ ((line & 7) << 4);
        gar[rd] = line + ((u >> 6) & 1) * 128;
        gac[rd] = u & 63;
    }
    #pragma unroll
    for (int rd = 0; rd < BRD; ++rd) {
        const int p = rd * (THREADS * 16) + tid * 16;
        const int line = p >> 7, s16 = (p >> 4) & 7;
        const int u = (s16 * 16) ^ ((line & 7) << 4);
        gbr[rd] = line + ((u >> 6) & 1) * LB;
        gbc[rd] = u & 63;
    }

    const char* Ag = (const char*)A + (size_t)m0 * Kb;
    const char* Bg = (const char*)B + (size_t)n0 * Kb;

    auto stage = [&](int h, int slot) {
        const size_t kby = (size_t)h << 6;
        #pragma unroll
        for (int rd = 0; rd < ARD; ++rd)
            gload_lds16(Ag + (size_t)gar[rd] * Kb + kby + gac[rd],
                        lds + slot * ASL + rd * (THREADS * 16) + w * 1024);
        #pragma unroll
        for (int rd = 0; rd < BRD; ++rd)
            gload_lds16(Bg + (size_t)gbr[rd] * Kb + kby + gbc[rd],
                        ldsB + slot * BSL + rd * (THREADS * 16) + w * 1024);
    };

    // read offsets (swizzle matches staging inversion)
    int offA[8], offB[4];
    #pragma unroll
    for (int mi = 0; mi < 8; ++mi) {
        const int row = wr * 128 + mi * 16 + l15;
        offA[mi] = (row & 127) * 128 + ((((row >> 7) * 64) + lg * 16) ^ ((row & 7) << 4));
    }
    #pragma unroll
    for (int nj = 0; nj < 4; ++nj) {
        const int row = wc * 64 + nj * 16 + l15;
        offB[nj] = (row & (LB - 1)) * 128 +
                   ((((row / LB) * 64) + lg * 16) ^ ((row & 7) << 4));
    }

    f32x4 acc[8][4] = {};

    auto compute = [&](int hh, int slot) {
        const char* la = lds + slot * ASL;
        const char* lb = ldsB + slot * BSL;
        bf16x8 af[8], bf[4];
        #pragma unroll
        for (int mi = 0; mi < 8; ++mi) af[mi] = *(const bf16x8*)(la + offA[mi]);
        #pragma unroll
        for (int nj = 0; nj < 4; ++nj) bf[nj] = *(const bf16x8*)(lb + offB[nj]);
        __builtin_amdgcn_s_setprio(1);
        #pragma unroll
        for (int mi = 0; mi < 8; ++mi)
            #pragma unroll
            for (int nj = 0; nj < 4; ++nj)
                acc[mi][nj] = __builtin_amdgcn_mfma_f32_16x16x32_bf16(af[mi], bf[nj], acc[mi][nj], 0, 0, 0);
        __builtin_amdgcn_s_setprio(0);
    };

    // prologue: 2 stages in flight; wait for the first
    stage(0, 0); stage(1, 1);
    waitvm<LPS>();
    pipe_barrier();

    int cur = 0, nx2 = 2;
    for (int h = 0; h < H - 2; ++h) {
        compute(h, cur);
        stage(h + 2, nx2);
        waitvm<LPS>();          // retire h+1's own loads; barrier globalizes
        pipe_barrier();
        cur = (cur == 2) ? 0 : cur + 1;
        nx2 = (nx2 == 2) ? 0 : nx2 + 1;
    }
    compute(H - 2, cur);
    waitvm<0>();
    pipe_barrier();
    cur = (cur == 2) ? 0 : cur + 1;
    compute(H - 1, cur);

    // epilogue
    const int r00 = m0 + wr * 128 + (lg << 2);
    const int c00 = n0 + wc * 64 + l15;
    #pragma unroll
    for (int nj = 0; nj < 4; ++nj) {
        const int c = c00 + nj * 16;
        if (MODE == 0) {
            const int which = c >> 10, hc = c & 1023;
            const int hh = hc >> 6, d = hc & 63;
            const float sc2 = (which == 0) ? 0.125f : 1.0f;
            u16* outp = outh + (size_t)which * ((size_t)NTOK * HID);
            #pragma unroll
            for (int mi = 0; mi < 8; ++mi)
                #pragma unroll
                for (int j = 0; j < 4; ++j) {
                    const int r = r00 + mi * 16 + j;
                    const int b = r >> 11, t = r & (SEQ - 1);
                    outp[((size_t)(b * NH + hh) * SEQ + t) * HD + d] = f2bf(acc[mi][nj][j] * sc2);
                }
        } else if (MODE == 1) {
            const float bi = bias[c];
            #pragma unroll
            for (int mi = 0; mi < 8; ++mi)
                #pragma unroll
                for (int j = 0; j < 4; ++j) {
                    const int r = r00 + mi * 16 + j;
                    const size_t idx = (size_t)r * N + c;
                    outf[idx] = resid[idx] + acc[mi][nj][j] + bi;
                }
        } else {
            const float bi = bias[c];
            #pragma unroll
            for (int mi = 0; mi < 8; ++mi)
                #pragma unroll
                for (int j = 0; j < 4; ++j) {
                    const int r = r00 + mi * 16 + j;
                    const float v = acc[mi][nj][j] + bi;
                    outh[(size_t)r * N + c] = f2bf(v > 0.f ? v : 0.f);
                }
        }
    }
}

// ---------------- Flash attention (causal), swapped-QK^T 32x32, in-reg softmax ----------------
// Paired q-tiles: block kpair handles qt=kpair then qt=15-kpair -> uniform 36
// tiles per block; grid (8, B*NH) = 512 blocks (2/CU, 8 waves/CU steady).
__global__ __launch_bounds__(256) void attn_kernel(const u16* __restrict__ Q,
                                                   const u16* __restrict__ K,
                                                   const u16* __restrict__ Vt,
                                                   u16* __restrict__ O) {
    __shared__ u16 Kl[2][64 * 64];
    __shared__ u16 Vl[2][64 * 64];
    const int kpair = blockIdx.x;
    const int bh = blockIdx.y;
    const int tid = threadIdx.x, w = tid >> 6, l = tid & 63;
    const int q32 = l & 31, hi = l >> 5;

    const u16* Kg0 = K + (size_t)bh * SEQ * HD;
    const u16* Vg0 = Vt + (size_t)bh * HD * SEQ;
    const int sr8 = tid >> 3;            // staging row 0..31 (+32 per round)
    const int sc8 = (tid & 7) * 16;      // staging col byte, 8 slots/row

    bf16x8 kreg[2], vreg[2];
    auto load_tile = [&](int st) {
        const char* Kg = (const char*)(Kg0 + (size_t)st * 64 * HD);
        const char* Vg = (const char*)(Vg0 + st * 64);
        #pragma unroll
        for (int it = 0; it < 2; it++) {
            kreg[it] = *(const bf16x8*)(Kg + (size_t)(it * 32 + sr8) * 128 + sc8);
            vreg[it] = *(const bf16x8*)(Vg + (size_t)(it * 32 + sr8) * (SEQ * 2) + sc8);
        }
    };
    auto write_tile = [&](int buf) {
        char* KlB = (char*)Kl[buf];
        char* VlB = (char*)Vl[buf];
        const int sw = (sr8 & 7) << 4;
        #pragma unroll
        for (int it = 0; it < 2; it++) {
            *(bf16x8*)(KlB + (it * 32 + sr8) * 128 + (sc8 ^ sw)) = kreg[it];
            *(bf16x8*)(VlB + (it * 32 + sr8) * 128 + (sc8 ^ sw)) = vreg[it];
        }
    };

    for (int ph = 0; ph < 2; ++ph) {
        const int qt = ph ? (SEQ / 128 - 1) - kpair : kpair;
        const int qbase = qt * 128 + w * 32;
        const int qrow = qbase + q32;

        const u16* Qg = Q + ((size_t)bh * SEQ + qrow) * HD;
        bf16x8 qf[4];
        #pragma unroll
        for (int c = 0; c < 4; ++c)
            qf[c] = *(const bf16x8*)&Qg[c * 16 + hi * 8];

        f32x16 oa[2] = {};
        float m = -1e30f, lsum = 0.f;

        const int ntiles = 2 * qt + 2;
        const int tlast = (qbase + 31) >> 6;

        load_tile(0);
        write_tile(0);

        for (int st = 0; st < ntiles; ++st) {
            const int cur = st & 1;
            __syncthreads();
            const bool pf = (st + 1 < ntiles);
            if (pf) load_tile(st + 1);

            if (st <= tlast) {
                const char* KlB = (const char*)Kl[cur];
                const char* VlB = (const char*)Vl[cur];

                f32x16 s[2];
                __builtin_amdgcn_s_setprio(1);
                #pragma unroll
                for (int a = 0; a < 2; ++a) {
                    const int row = a * 32 + q32;
                    const char* base = KlB + row * 128;
                    const int sw = (row & 7) << 4;
                    f32x16 accs = {};
                    #pragma unroll
                    for (int ds4 = 0; ds4 < 4; ++ds4) {
                        bf16x8 kf = *(const bf16x8*)(base + ((ds4 * 32 + hi * 16) ^ sw));
                        accs = __builtin_amdgcn_mfma_f32_32x32x16_bf16(kf, qf[ds4], accs, 0, 0, 0);
                    }
                    s[a] = accs;
                }
                __builtin_amdgcn_s_setprio(0);

                if (st == tlast) {
                    const int st64 = st * 64;
                    #pragma unroll
                    for (int a = 0; a < 2; ++a)
                        #pragma unroll
                        for (int r = 0; r < 16; ++r) {
                            const int kvg = st64 + a * 32 + (r & 3) + 8 * (r >> 2) + 4 * hi;
                            if (kvg > qrow) s[a][r] = -1e30f;
                        }
                }

                float pm0 = -1e30f, pm1 = -1e30f, pm2 = -1e30f, pm3 = -1e30f;
                #pragma unroll
                for (int r = 0; r < 16; r += 4) {
                    pm0 = fmaxf(pm0, fmaxf(s[0][r + 0], s[1][r + 0]));
                    pm1 = fmaxf(pm1, fmaxf(s[0][r + 1], s[1][r + 1]));
                    pm2 = fmaxf(pm2, fmaxf(s[0][r + 2], s[1][r + 2]));
                    pm3 = fmaxf(pm3, fmaxf(s[0][r + 3], s[1][r + 3]));
                }
                float pmax = fmaxf(fmaxf(pm0, pm1), fmaxf(pm2, pm3));
                pmax = fmaxf(pmax, __shfl_xor(pmax, 32, 64));

                if (!__all(pmax <= m + 8.f)) {
                    const float newm = fmaxf(m, pmax);
                    const float sc = __expf(m - newm);
                    m = newm;
                    lsum *= sc;
                    #pragma unroll
                    for (int d = 0; d < 2; ++d)
                        #pragma unroll
                        for (int r = 0; r < 16; ++r)
                            oa[d][r] *= sc;
                }

                float s0 = 0.f, s1 = 0.f, s2 = 0.f, s3 = 0.f;
                #pragma unroll
                for (int a = 0; a < 2; ++a)
                    #pragma unroll
                    for (int r = 0; r < 16; r += 4) {
                        float p0 = __expf(s[a][r + 0] - m);
                        float p1 = __expf(s[a][r + 1] - m);
                        float p2 = __expf(s[a][r + 2] - m);
                        float p3 = __expf(s[a][r + 3] - m);
                        s[a][r + 0] = p0; s[a][r + 1] = p1;
                        s[a][r + 2] = p2; s[a][r + 3] = p3;
                        s0 += p0; s1 += p1; s2 += p2; s3 += p3;
                    }
                float psum = (s0 + s1) + (s2 + s3);
                psum += __shfl_xor(psum, 32, 64);
                lsum += psum;

                u32 W[2][4][2];
                #pragma unroll
                for (int a = 0; a < 2; ++a)
                    #pragma unroll
                    for (int i = 0; i < 4; ++i) {
                        W[a][i][0] = cvtpk(s[a][4 * i + 0], s[a][4 * i + 1]);
                        W[a][i][1] = cvtpk(s[a][4 * i + 2], s[a][4 * i + 3]);
                    }
                bf16x8 pa[4];
                #pragma unroll
                for (int a = 0; a < 2; ++a)
                    #pragma unroll
                    for (int j = 0; j < 2; ++j) {
                        u32 a0 = W[a][2 * j][0], b0 = W[a][2 * j + 1][0];
                        u32 a1 = W[a][2 * j][1], b1 = W[a][2 * j + 1][1];
                        plswap(a0, b0);
                        plswap(a1, b1);
                        union { u32 ww[4]; bf16x8 v; } u_;
                        u_.ww[0] = a0; u_.ww[1] = a1; u_.ww[2] = b0; u_.ww[3] = b1;
                        pa[2 * a + j] = u_.v;
                    }

                __builtin_amdgcn_s_setprio(1);
                #pragma unroll
                for (int dblk = 0; dblk < 2; ++dblk) {
                    const int row = dblk * 32 + q32;
                    const char* base = VlB + row * 128;
                    const int sw = (row & 7) << 4;
                    #pragma unroll
                    for (int s4 = 0; s4 < 4; ++s4) {
                        bf16x8 vf = *(const bf16x8*)(base + ((s4 * 32 + hi * 16) ^ sw));
                        oa[dblk] = __builtin_amdgcn_mfma_f32_32x32x16_bf16(vf, pa[s4], oa[dblk], 0, 0, 0);
                    }
                }
                __builtin_amdgcn_s_setprio(0);
            }

            if (pf) write_tile(cur ^ 1);
        }

        // epilogue: O[qrow][d] = oa/lsum, concat-head layout
        const int b = bh >> 4, h = bh & 15;
        const float inv = 1.f / lsum;
        u16* Orow = O + ((size_t)b * SEQ + qrow) * HID + h * HD;
        #pragma unroll
        for (int dblk = 0; dblk < 2; ++dblk)
            #pragma unroll
            for (int i = 0; i < 4; ++i) {
                ushort4 st4;
                st4.x = f2bf(oa[dblk][4 * i + 0] * inv);
                st4.y = f2bf(oa[dblk][4 * i + 1] * inv);
                st4.z = f2bf(oa[dblk][4 * i + 2] * inv);
                st4.w = f2bf(oa[dblk][4 * i + 3] * inv);
                *(ushort4*)&Orow[dblk * 32 + 8 * i + 4 * hi] = st4;
            }

        __syncthreads();   // next phase's write_tile(0) must not race this phase's reads
    }
}

// ---------------- launch ----------------
extern "C" void kernel_launch(void* const* d_in, const int* in_sizes, int n_in,
                              void* d_out, int out_size, void* d_ws, size_t ws_size,
                              hipStream_t stream) {
    (void)in_sizes; (void)n_in; (void)out_size; (void)ws_size;
    const float* x   = (const float*)d_in[0];
    const float* Wq  = (const float*)d_in[1];
    const float* Wk  = (const float*)d_in[2];
    const float* Wv  = (const float*)d_in[3];
    const float* Wo  = (const float*)d_in[4];
    const float* bo  = (const float*)d_in[5];
    const float* W1  = (const float*)d_in[6];
    const float* b1  = (const float*)d_in[7];
    const float* W2  = (const float*)d_in[8];
    const float* b2  = (const float*)d_in[9];
    const float* g1  = (const float*)d_in[10];
    const float* be1 = (const float*)d_in[11];
    const float* g2  = (const float*)d_in[12];
    const float* be2 = (const float*)d_in[13];
    float* out = (float*)d_out;

    char* ws = (char*)d_ws;
    size_t off = 0;
    auto alloc = [&](size_t bytes) { void* p = ws + off; off += bytes; return p; };
    u16* Wqkv_t = (u16*)alloc((size_t)3 * HID * HID * 2);
    u16* Wo_t = (u16*)alloc((size_t)HID * HID * 2);
    u16* W1_t = (u16*)alloc((size_t)DFF * HID * 2);
    u16* W2_t = (u16*)alloc((size_t)HID * DFF * 2);
    u16* h1   = (u16*)alloc((size_t)NTOK * HID * 2);   // reused as h2
    u16* Qb   = (u16*)alloc((size_t)NTOK * HID * 2);
    u16* Kb   = (u16*)alloc((size_t)NTOK * HID * 2);
    u16* Vb   = (u16*)alloc((size_t)NTOK * HID * 2);   // reused as attn_out
    u16* Vt   = (u16*)alloc((size_t)NTOK * HID * 2);
    float* x2 = (float*)alloc((size_t)NTOK * HID * 4);
    u16* ff1  = Qb;

    transpose_w<<<dim3(32, 2, 16), 256, 0, stream>>>(Wq, Wqkv_t, HID, HD);
    transpose_w<<<dim3(32, 2, 16), 256, 0, stream>>>(Wk, Wqkv_t + (size_t)HID * HID, HID, HD);
    transpose_w<<<dim3(32, 2, 16), 256, 0, stream>>>(Wv, Wqkv_t + (size_t)2 * HID * HID, HID, HD);
    transpose_w<<<dim3(32, 32, 1), 256, 0, stream>>>(Wo, Wo_t, HID, HID);
    transpose_w<<<dim3(32, 128, 1), 256, 0, stream>>>(W1, W1_t, HID, DFF);
    transpose_w<<<dim3(128, 32, 1), 256, 0, stream>>>(W2, W2_t, DFF, HID);

    ln_kernel<<<NTOK, 256, 0, stream>>>(x, g1, be1, h1);

    // merged QKV: [8192 x 3072], 8-wave 256x256 blocks, grid 384
    gemm6<8, 0><<<dim3(32 * 12), 512, 0, stream>>>(h1, Wqkv_t, nullptr, Qb,
                                                   nullptr, nullptr, HID, 3072);

    transpose_v<<<dim3(SEQ / 64, BATCH * NH), 256, 0, stream>>>(Vb, Vt);

    u16* attn_out = Vb;
    attn_kernel<<<dim3(SEQ / 256, BATCH * NH), 256, 0, stream>>>(Qb, Kb, Vt, attn_out);

    // x2 = x + attn_out @ Wo + bo : 4-wave 256x128 blocks, grid 256
    gemm6<4, 1><<<dim3(32 * 8), 256, 0, stream>>>(attn_out, Wo_t, x2, nullptr, bo, x, HID, HID);

    ln_kernel<<<NTOK, 256, 0, stream>>>(x2, g2, be2, h1);

    // ff1 = relu(h2 @ W1 + b1): [8192 x 4096], 8-wave, grid 512
    gemm6<8, 2><<<dim3(32 * 16), 512, 0, stream>>>(h1, W1_t, nullptr, ff1, b1, nullptr, HID, DFF);

    // out = x2 + ff1 @ W2 + b2: K=4096, 4-wave, grid 256
    gemm6<4, 1><<<dim3(32 * 8), 256, 0, stream>>>(ff1, W2_t, out, nullptr, b2, x2, DFF, HID);
}